// Round 18
// baseline (84.400 us; speedup 1.0000x reference)
//
#include <hip/hip_runtime.h>
#include <math.h>

#define HH 32
#define WW 32
#define CIN 64
#define NO 64
#define NCK 576                 // CIN*9
#define X_ELEMS 262144
#define W16S 65                 // u16 W row stride (65: staggers banks)

__device__ __forceinline__ float fexp2(float x) {
#if __has_builtin(__builtin_amdgcn_exp2f)
    return __builtin_amdgcn_exp2f(x);
#else
    return exp2f(x);
#endif
}
__device__ __forceinline__ float flog2(float x) {
#if __has_builtin(__builtin_amdgcn_logf)
    return __builtin_amdgcn_logf(x);
#else
    return log2f(x);
#endif
}

// Single dispatch, occupancy-preserving fusion (fixes R17's 1-block/CU):
// block = 1024 thr = 16 waves = 8 pixels x 2 c-halves; grid = 512 = 2
// blocks/CU = 32 waves/CU (R14's occupancy). LDS: W quantized to u16
// fixed-point (theta in [0,8], ulp 1.2e-4 -> output err ~0.1 << 1.22):
// 74.9 KB + tau 2.6 KB + part 2 KB = 79.5 KB -> fits 2 blocks/CU.
__global__ __launch_bounds__(1024) void ekv_kernel(
        const float* __restrict__ x, const float* __restrict__ theta,
        float* __restrict__ out) {
    constexpr float SZ  = 19.235933878519512f;   // log2(e)/0.075
    constexpr float SZQ = 19.235933878519512f / 8192.0f;  // decode scale
    constexpr float C2  = 1.2726342e-3f;         // 2^(-D2), D2 = 0.5/(0.075*ln2)
    constexpr float OS  = 0.020018875579925058f; // ln2^2 * 2e-6 * 500000/24

    __shared__ unsigned short W16[NCK * W16S];   // 74880 B
    __shared__ float taul[NCK + 64];             // 2560 B (pad: never active)
    __shared__ float part[8][64];                // 2048 B

    const int t = threadIdx.x;

    // ---- stage W16 (coalesced theta reads; LDS u16 scatter, stride-65) ----
#pragma unroll
    for (int j = 0; j < 36; ++j) {               // 36864 / 1024
        int i  = t + 1024 * j;                   // i = o*576 + ck (theta flat)
        int o  = i / NCK;
        int ck = i - NCK * o;
        float th = theta[i];
        float uq = th * 8192.0f + 0.5f;          // [0,8] -> [0,65536)
        uq = fminf(fmaxf(uq, 0.0f), 65535.0f);
        W16[ck * W16S + o] = (unsigned short)uq;
    }
    // ---- tau[ck] = SZ*min_o theta - 8 (64 coalesced sweeps over o) ----
    if (t < NCK) {
        float mn = 1e30f;
        for (int o = 0; o < 64; ++o) mn = fminf(mn, theta[o * NCK + t]);
        taul[t] = SZ * mn - 8.0f;                // active iff z >= -8
    } else if (t < NCK + 64) {
        taul[t] = 1e30f;                         // pad
    }
    __syncthreads();

    const int lane = t & 63;
    const int wv   = __builtin_amdgcn_readfirstlane(t >> 6);  // 0..15
    const int p2   = (int)blockIdx.x * 16 + wv;  // pixel-half id
    const int pix  = p2 >> 1, half = p2 & 1;
    const int px   = wv >> 1;                    // pixel slot within block
    const int n  = pix >> 10;
    const int ho = (pix >> 5) & 31;
    const int wo = pix & 31;
    const int c0 = half * 32;

    // lane l -> (c_off = l/9, tap k = l%9); lane 63 decode-clamped + masked
    int l = lane;
    int c_off = l / 9; if (c_off > 6) c_off = 6;
    int k = l - 9 * c_off; if (k > 8) k = 8;
    int di = k / 3, dj = k - 3 * (k / 3);
    int h = ho + di - 1, w_ = wo + dj - 1;
    bool sval = (h >= 0) && (h < HH) && (w_ >= 0) && (w_ < WW);
    int hc = min(max(h, 0), HH - 1), wc = min(max(w_, 0), WW - 1);
    // pad taps: xs = 0 == exact x=0 contribution if ever active; else skipped
    float msc = ((l < 63) && sval) ? SZ : 0.0f;

    int gidx = n * (CIN * HH * WW) + (c0 + c_off) * 1024 + hc * WW + wc;

    float accF = 0.f, accR = 0.f;

    float xv = x[min(gidx, X_ELEMS - 1)];        // chunk 0 (OOB lanes masked)
    float tv = taul[c0 * 9 + l];

#define EKV_BODY(II, WU, EN)                                               \
    {                                                                      \
        int xb = __builtin_amdgcn_readlane(                                \
                     __builtin_bit_cast(int, xs), (II));                   \
        float sx = __builtin_bit_cast(float, xb);                          \
        float uf = (float)(WU);                                            \
        float z  = (EN) ? fmaf(uf, -SZQ, sx) : -200.0f;                    \
        float e  = fexp2(z);                                               \
        float f  = flog2(1.0f + e);                                        \
        float rr = flog2(fmaf(C2, e, 1.0f));                               \
        accF = fmaf(f, f, accF);                                           \
        accR = fmaf(rr, rr, accR);                                         \
    }

    for (int cb = 0; cb < 32; cb += 7) {
        int cc = 32 - cb; if (cc > 7) cc = 7;
        // prefetch next chunk (x global + tau LDS) before processing this one
        int gidx2 = gidx + 7 * 1024;
        float xvn = xv, tvn = tv;
        if (cb + 7 < 32) {
            xvn = x[min(gidx2, X_ELEMS - 1)];
            tvn = taul[(c0 + cb + 7) * 9 + l];
        }

        float xs = xv * msc;                     // SZ*x (pad lanes: 0)
        bool a = (xs >= tv) && (l < cc * 9);
        unsigned long long m = __ballot(a);

        const int cb9 = (c0 + cb) * 9;           // ck = cb9 + il
        while (m) {
            int i0 = (int)__builtin_ctzll(m);             m &= m - 1;
            bool h1 = m != 0;
            int i1 = m ? (int)__builtin_ctzll(m) : 0;     m &= m - 1;
            bool h2 = m != 0;
            int i2 = m ? (int)__builtin_ctzll(m) : 0;     m &= m - 1;
            bool h3 = m != 0;
            int i3 = m ? (int)__builtin_ctzll(m) : 0;     m &= m - 1;
            // 4 LDS W-row reads (u16, lanes consecutive -> ~2-way = free)
            unsigned short U0 = W16[(cb9 + i0) * W16S + lane];
            unsigned short U1 = W16[(cb9 + i1) * W16S + lane];
            unsigned short U2 = W16[(cb9 + i2) * W16S + lane];
            unsigned short U3 = W16[(cb9 + i3) * W16S + lane];
            EKV_BODY(i0, U0, true)
            EKV_BODY(i1, U1, h1)
            EKV_BODY(i2, U2, h2)
            EKV_BODY(i3, U3, h3)
        }
        gidx = gidx2; xv = xvn; tv = tvn;
    }
#undef EKV_BODY

    float p = accF - accR;
    if (half == 1) part[px][lane] = p;
    __syncthreads();
    if (half == 0)
        out[((n * NO + lane) * HH + ho) * WW + wo] = (p + part[px][lane]) * OS;
}

extern "C" void kernel_launch(void* const* d_in, const int* in_sizes, int n_in,
                              void* d_out, int out_size, void* d_ws, size_t ws_size,
                              hipStream_t stream) {
    const float* x     = (const float*)d_in[0];   // (4,64,32,32) fp32
    const float* theta = (const float*)d_in[1];   // (64,64,3,3) fp32
    float* out = (float*)d_out;                   // (4,64,32,32) fp32

    ekv_kernel<<<512, 1024, 0, stream>>>(x, theta, out);  // single dispatch
}

// Round 19
// 73.271 us; speedup vs baseline: 1.1519x; 1.1519x over previous
//
#include <hip/hip_runtime.h>
#include <math.h>

#define HH 32
#define WW 32
#define CIN 64
#define NO 64
#define NCK 576                 // CIN*9
#define X_ELEMS 262144
#define STRIDE_E 292            // LDS worklist entries per pixel-half (288+pad, 16B-aligned rows)

// ws float-offsets
#define WS_W    0               // Wz[ck][o] = -SZ*theta[o][ck]  (36864, coalesced in o)
#define WS_TAU  36864           // tau[ck] = SZ*min_o theta - 8, +64 pad(1e30)

__device__ __forceinline__ float fexp2(float x) {
#if __has_builtin(__builtin_amdgcn_exp2f)
    return __builtin_amdgcn_exp2f(x);
#else
    return exp2f(x);
#endif
}
__device__ __forceinline__ float flog2(float x) {
#if __has_builtin(__builtin_amdgcn_logf)
    return __builtin_amdgcn_logf(x);
#else
    return log2f(x);
#endif
}

__global__ __launch_bounds__(256) void prep_kernel(const float* __restrict__ theta,
                                                   float* __restrict__ ws) {
    constexpr float SZ = 19.235933878519512f;    // log2(e)/0.075
    const int b = blockIdx.x, t = threadIdx.x;
    if (b < 144) {                               // W transform + in-wave tau min
        int i = b * 256 + t;                     // i = ck*64 + o; lanes are o
        int o = i & 63, ck = i >> 6;
        float th = theta[o * NCK + ck];
        ws[WS_W + i] = -SZ * th;
        float mn = th;                           // wave-min over the 64 o's
#pragma unroll
        for (int s = 32; s > 0; s >>= 1)
            mn = fminf(mn, __shfl_xor(mn, s, 64));
        if (o == 0) ws[WS_TAU + ck] = SZ * mn - 8.0f;   // active iff z >= -8
    } else {                                     // tau pad: never active
        if (t < 64) ws[WS_TAU + NCK + t] = 1e30f;
    }
}

// Single main kernel: block = 512 thr = 8 waves = 4 pixels x 2 c-halves.
// Phase A (per wave, no barrier needed -- wave consumes its own list): test
// 7ch x 9taps per ballot, mbcnt-compact actives into an LDS worklist.
// Phase B (per wave): fixed-trip loop over worklist quads (uniform
// ds_read_b128, prefetched), 4 pipelined global W-row loads + 4 exp2/log2
// bodies per round. No ballot/ctz/readlane in the evaluation loop.
__global__ __launch_bounds__(512) void ekv_kernel(
        const float* __restrict__ x, const float* __restrict__ ws,
        float* __restrict__ out) {
    constexpr float SZ = 19.235933878519512f;    // log2(e)/0.075
    constexpr float C2 = 1.2726342e-3f;          // 2^(-D2), D2 = 0.5/(0.075*ln2)
    constexpr float OS = 0.020018875579925058f;  // ln2^2 * 2e-6 * 500000/24

    __shared__ int   lcm[8][STRIDE_E];           // ck worklists (per wave)
    __shared__ float lxm[8][STRIDE_E];           // xs worklists
    __shared__ float part[4][64];

    const int t    = threadIdx.x;
    const int lane = t & 63;
    const int wv   = __builtin_amdgcn_readfirstlane(t >> 6);  // 0..7
    const int p2   = (int)blockIdx.x * 8 + wv;   // pixel-half id
    const int pix  = p2 >> 1, half = p2 & 1;
    const int px   = wv >> 1;                    // pixel slot within block
    const int n  = pix >> 10;
    const int ho = (pix >> 5) & 31;
    const int wo = pix & 31;
    const int c0 = half * 32;

    // ---- Phase A: build this wave's worklist in LDS ----
    int l = lane;
    int c_off = l / 9; if (c_off > 6) c_off = 6;
    int k = l - 9 * c_off; if (k > 8) k = 8;
    int di = k / 3, dj = k - 3 * (k / 3);
    int h = ho + di - 1, w_ = wo + dj - 1;
    bool sval = (h >= 0) && (h < HH) && (w_ >= 0) && (w_ < WW);
    int hc = min(max(h, 0), HH - 1), wc = min(max(w_, 0), WW - 1);
    // pad taps: xs = 0 == exact x=0 contribution if ever active; else skipped
    float msc = ((l < 63) && sval) ? SZ : 0.0f;

    int gidx = n * (CIN * HH * WW) + (c0 + c_off) * 1024 + hc * WW + wc;
    const float* tw = ws + WS_TAU + c0 * 9;

    int cnt = 0;
    float xv = x[min(gidx, X_ELEMS - 1)];        // chunk 0 (OOB lanes masked)
    float tv = tw[l];

    for (int cb = 0; cb < 32; cb += 7) {
        int cc = 32 - cb; if (cc > 7) cc = 7;
        int gidx2 = gidx + 7 * 1024;
        const float* tw2 = tw + 63;
        float xvn = xv, tvn = tv;
        if (cb + 7 < 32) { xvn = x[min(gidx2, X_ELEMS - 1)]; tvn = tw2[l]; }

        float xs = xv * msc;                     // SZ*x (pad lanes: 0)
        bool a = (xs >= tv) && (l < cc * 9);
        unsigned long long act = __ballot(a);
        unsigned lo32 = (unsigned)act, hi32 = (unsigned)(act >> 32);
        int idx = __builtin_amdgcn_mbcnt_hi(hi32,
                      __builtin_amdgcn_mbcnt_lo(lo32, 0));
        if (a) {
            lcm[wv][cnt + idx] = (c0 + cb) * 9 + l;   // ck
            lxm[wv][cnt + idx] = xs;                  // SZ*x
        }
        cnt += (int)__popcll(act);               // uniform across lanes
        gidx = gidx2; tw = tw2; xv = xvn; tv = tvn;
    }
    // pad to a multiple of 4 with exact-zero dummies (z=-1e5 -> exp2 -> 0)
    int padn = (-cnt) & 3;
    if (lane < padn) { lcm[wv][cnt + lane] = 0; lxm[wv][cnt + lane] = -100000.0f; }
    const int rounds = (cnt + padn) >> 2;        // uniform

    // ---- Phase B: fixed-trip quad evaluation over this wave's list ----
    const int4*   LC = (const int4*)&lcm[wv][0]; // rows are 16B-aligned (292*4)
    const float4* LX = (const float4*)&lxm[wv][0];
    const float* wsW = ws + WS_W;

    float accF = 0.f, accR = 0.f;

#define EKV_BODY(SX, WV)                                                   \
    {                                                                      \
        float z  = (WV) + (SX);      /* SZ*(x - theta) */                  \
        float e  = fexp2(z);                                               \
        float f  = flog2(1.0f + e);                                        \
        float rr = flog2(fmaf(C2, e, 1.0f));                               \
        accF = fmaf(f, f, accF);                                           \
        accR = fmaf(rr, rr, accR);                                         \
    }

    if (rounds > 0) {
        int4   cq = LC[0];
        float4 xq = LX[0];
        for (int r = 0; r < rounds; ++r) {
            int4 cqn = cq; float4 xqn = xq;
            if (r + 1 < rounds) { cqn = LC[r + 1]; xqn = LX[r + 1]; }
            // 4 coalesced W-row loads issued before any body
            float W0 = wsW[(cq.x << 6) + lane];
            float W1 = wsW[(cq.y << 6) + lane];
            float W2 = wsW[(cq.z << 6) + lane];
            float W3 = wsW[(cq.w << 6) + lane];
            EKV_BODY(xq.x, W0)
            EKV_BODY(xq.y, W1)
            EKV_BODY(xq.z, W2)
            EKV_BODY(xq.w, W3)
            cq = cqn; xq = xqn;
        }
    }
#undef EKV_BODY

    float p = accF - accR;
    if (half == 1) part[px][lane] = p;
    __syncthreads();
    if (half == 0)
        out[((n * NO + lane) * HH + ho) * WW + wo] = (p + part[px][lane]) * OS;
}

extern "C" void kernel_launch(void* const* d_in, const int* in_sizes, int n_in,
                              void* d_out, int out_size, void* d_ws, size_t ws_size,
                              hipStream_t stream) {
    const float* x     = (const float*)d_in[0];   // (4,64,32,32) fp32
    const float* theta = (const float*)d_in[1];   // (64,64,3,3) fp32
    float* out = (float*)d_out;                   // (4,64,32,32) fp32
    float* ws  = (float*)d_ws;

    prep_kernel<<<145, 256, 0, stream>>>(theta, ws);
    ekv_kernel <<<1024, 512, 0, stream>>>(x, ws, out);  // build+eval fused
}